// Round 6
// baseline (470.904 us; speedup 1.0000x reference)
//
#include <hip/hip_runtime.h>
#include <stdint.h>

#define S_ 512
#define B_ 64
#define V_ 50000
#define E_ 300
#define H_ 256
#define C_ 5

typedef _Float16 h8_t __attribute__((ext_vector_type(8)));
typedef float f32x4 __attribute__((ext_vector_type(4)));

// tanh(x) = 1 - 2/(e^{2x}+1); e^{2x}=2^{2x*log2e}. No clamp needed:
// x->-inf: e->0 -> -1; x->+inf: e->inf, rcp(inf)=0 -> +1.
__device__ __forceinline__ float fast_tanh(float x) {
    float e = __builtin_amdgcn_exp2f(x * 2.88539008177793f);  // 2*log2(e)
    return fmaf(-2.0f, __builtin_amdgcn_rcpf(e + 1.0f), 1.0f);
}

// ---------------------------------------------------------------------------
// Kernel A: transpose W_ih (H,E) -> WT (E,H)
// ---------------------------------------------------------------------------
__global__ void transpose_kernel(const float* __restrict__ W_ih,
                                 float* __restrict__ WT) {
    int i = blockIdx.x * 256 + threadIdx.x;
    if (i < E_ * H_) {
        int e = i / H_;
        int h = i - e * H_;
        WT[i] = W_ih[h * E_ + e];
    }
}

// ---------------------------------------------------------------------------
// Kernel B: xw[s,b,h] = sum_e emb[idx[s,b],e]*W_ih[h,e] + b_ih[h] + b_hh[h]
// ---------------------------------------------------------------------------
__global__ __launch_bounds__(256, 2) void xw_kernel(
    const int* __restrict__ idx, const float* __restrict__ emb,
    const float* __restrict__ WT, const float* __restrict__ b_ih,
    const float* __restrict__ b_hh, float* __restrict__ xw) {
    __shared__ float xs[64 * E_];  // 76.8 KB
    const int base = blockIdx.x * 64;
    const int tid = threadIdx.x;
    const int rq = tid >> 5;  // 0..7  -> rows 8rq..8rq+7
    const int hq = tid & 31;  // 0..31 -> cols 8hq..8hq+7

    for (int t = tid; t < 64 * 75; t += 256) {
        int r = t / 75;
        int c = t - r * 75;
        float4 v = *(const float4*)(emb + (size_t)idx[base + r] * E_ + 4 * c);
        *(float4*)(xs + r * E_ + 4 * c) = v;
    }
    __syncthreads();

    float acc[8][8];
#pragma unroll
    for (int u = 0; u < 8; ++u)
#pragma unroll
        for (int j = 0; j < 8; ++j) acc[u][j] = 0.0f;

    for (int e = 0; e < E_; e += 4) {
        const float* wp = WT + e * H_ + 8 * hq;
        float wv[4][8];
#pragma unroll
        for (int q = 0; q < 4; ++q) {
            float4 aa = *(const float4*)(wp + q * H_);
            float4 bb = *(const float4*)(wp + q * H_ + 4);
            wv[q][0] = aa.x; wv[q][1] = aa.y; wv[q][2] = aa.z; wv[q][3] = aa.w;
            wv[q][4] = bb.x; wv[q][5] = bb.y; wv[q][6] = bb.z; wv[q][7] = bb.w;
        }
#pragma unroll
        for (int u = 0; u < 8; ++u) {
            const float4 xv = *(const float4*)(xs + (8 * rq + u) * E_ + e);
#pragma unroll
            for (int j = 0; j < 8; ++j) {
                float t = fmaf(xv.x, wv[0][j], acc[u][j]);
                t = fmaf(xv.y, wv[1][j], t);
                t = fmaf(xv.z, wv[2][j], t);
                acc[u][j] = fmaf(xv.w, wv[3][j], t);
            }
        }
    }

    float bias[8];
    {
        float4 ba = *(const float4*)(b_ih + 8 * hq);
        float4 bb = *(const float4*)(b_ih + 8 * hq + 4);
        float4 ca = *(const float4*)(b_hh + 8 * hq);
        float4 cb = *(const float4*)(b_hh + 8 * hq + 4);
        bias[0] = ba.x + ca.x; bias[1] = ba.y + ca.y;
        bias[2] = ba.z + ca.z; bias[3] = ba.w + ca.w;
        bias[4] = bb.x + cb.x; bias[5] = bb.y + cb.y;
        bias[6] = bb.z + cb.z; bias[7] = bb.w + cb.w;
    }
#pragma unroll
    for (int u = 0; u < 8; ++u) {
        float4 o0, o1;
        o0.x = acc[u][0] + bias[0]; o0.y = acc[u][1] + bias[1];
        o0.z = acc[u][2] + bias[2]; o0.w = acc[u][3] + bias[3];
        o1.x = acc[u][4] + bias[4]; o1.y = acc[u][5] + bias[5];
        o1.z = acc[u][6] + bias[6]; o1.w = acc[u][7] + bias[7];
        float* op = xw + (size_t)(base + 8 * rq + u) * H_ + 8 * hq;
        *(float4*)op = o0;
        *(float4*)(op + 4) = o1;
    }
}

// ---------------------------------------------------------------------------
// Kernel C: MFMA recurrence. 4 blocks x 16 batch cols, 256 threads = 4 waves
// (1 wave/SIMD). Per step: D[256,16] = W_hh*H + xw (xw = C operand).
//
//   wave w owns rows 64w..64w+63 (4 M-tiles): A = 4x8 h8_t = 128 regs,
//   gfx950 unified VGPR/AGPR file; MFMA reads A from AGPR directly.
//   KEY vs R4: 4 waves instead of 8 -> B-fragment LDS reads halve
//   (each wave must read the full 8KB H regardless of M-tiles owned):
//   32 ds_read_b128/step (~384 cyc pipe) instead of 64 (~770).
//
//   H in LDS in B-FRAGMENT ORDER (conflict-free both sides):
//     byte(k, col n) = (k>>5)*1024 + ((k>>3)&3)*256 + n*16 + (k&7)*2
//   read:  lane l, slice ks -> b128 at ks*1024 + 16*l  (linear: 0 conflict)
//   write: lane (hi,n), tile mt -> b64 at const + n*16 (2-way = free)
//
//   Epilogue: 16x slim tanh (2 trans each), hsum in regs, cvt_pkrtz pack,
//   4 b64 writes. xw prefetched 2 steps ahead into future C registers.
//   One barrier per step; H double-buffered (2x8KB).
// ---------------------------------------------------------------------------
__global__ __launch_bounds__(256, 1) void rnn_kernel(
    const float* __restrict__ xw, const float* __restrict__ W_hh,
    float* __restrict__ hsum_out) {
    const int tid = threadIdx.x;
    const int w = tid >> 6;  // wave 0..3
    const int l = tid & 63;
    const int n = l & 15;   // batch col within block / A row / B col
    const int hi = l >> 4;  // k-group
    const int bbase = blockIdx.x * 16;
    const int rowbase = w * 64;

    __shared__ __attribute__((aligned(16))) unsigned char Hl[2][8192];
    char* lds = (char*)Hl;

    // ---- A fragments: W_hh rows rowbase..rowbase+63 as f16 ----
    // lane l holds A[m = l&15][k = ks*32 + (l>>4)*8 + j]
    h8_t a[4][8];
#pragma unroll
    for (int mt = 0; mt < 4; ++mt) {
        const float* wr = W_hh + (size_t)(rowbase + mt * 16 + n) * H_;
#pragma unroll
        for (int ks = 0; ks < 8; ++ks) {
            const float* wp = wr + ks * 32 + hi * 8;
            float4 f0 = *(const float4*)wp;
            float4 f1 = *(const float4*)(wp + 4);
            h8_t v;
            v[0] = (_Float16)f0.x; v[1] = (_Float16)f0.y;
            v[2] = (_Float16)f0.z; v[3] = (_Float16)f0.w;
            v[4] = (_Float16)f1.x; v[5] = (_Float16)f1.y;
            v[6] = (_Float16)f1.z; v[7] = (_Float16)f1.w;
            a[mt][ks] = v;
        }
    }

    // H'-write byte offsets (within a buffer): rows k0..k0+3, col n
    int wboff[4];
#pragma unroll
    for (int mt = 0; mt < 4; ++mt) {
        int k0 = rowbase + mt * 16 + hi * 4;
        wboff[mt] = ((k0 >> 5) << 10) + (((k0 >> 3) & 3) << 8) + (n << 4) +
                    ((k0 & 7) << 1);
    }

    // zero H buffer 0 (8 KB = 2048 dwords)
    for (int t = tid; t < 2048; t += 256) ((unsigned int*)Hl)[t] = 0u;

    f32x4 hs[4];
#pragma unroll
    for (int mt = 0; mt < 4; ++mt) hs[mt] = (f32x4)0.0f;

    // per-lane xw element base: xw[s][bbase+n][rowbase + mt*16 + hi*4 + r]
    const float* xwl = xw + (size_t)(bbase + n) * H_ + rowbase + hi * 4;
    // xw doubles as the MFMA C operand (prefetched 2 steps ahead)
    f32x4 cA[4], cB[4];
#pragma unroll
    for (int mt = 0; mt < 4; ++mt) {
        cA[mt] = *(const f32x4*)(xwl + mt * 16);          // s = 0
        cB[mt] = *(const f32x4*)(xwl + 16384 + mt * 16);  // s = 1
    }
    __syncthreads();

#define STEP(CUR, CV, SIDX)                                                    \
    {                                                                          \
        h8_t bf[8];                                                            \
        _Pragma("unroll") for (int ks = 0; ks < 8; ++ks)                       \
            bf[ks] = *(const h8_t*)(lds + (CUR)*8192 + ks * 1024 + l * 16);    \
        _Pragma("unroll") for (int ks = 0; ks < 8; ++ks) {                     \
            CV[0] = __builtin_amdgcn_mfma_f32_16x16x32_f16(a[0][ks], bf[ks],   \
                                                           CV[0], 0, 0, 0);    \
            CV[1] = __builtin_amdgcn_mfma_f32_16x16x32_f16(a[1][ks], bf[ks],   \
                                                           CV[1], 0, 0, 0);    \
            CV[2] = __builtin_amdgcn_mfma_f32_16x16x32_f16(a[2][ks], bf[ks],   \
                                                           CV[2], 0, 0, 0);    \
            CV[3] = __builtin_amdgcn_mfma_f32_16x16x32_f16(a[3][ks], bf[ks],   \
                                                           CV[3], 0, 0, 0);    \
        }                                                                      \
        _Pragma("unroll") for (int mt = 0; mt < 4; ++mt) {                     \
            float h0 = fast_tanh(CV[mt][0]);                                   \
            float h1 = fast_tanh(CV[mt][1]);                                   \
            float h2 = fast_tanh(CV[mt][2]);                                   \
            float h3 = fast_tanh(CV[mt][3]);                                   \
            hs[mt][0] += h0; hs[mt][1] += h1;                                  \
            hs[mt][2] += h2; hs[mt][3] += h3;                                  \
            uint2 pk;                                                          \
            pk.x = __builtin_bit_cast(unsigned int,                            \
                                      __builtin_amdgcn_cvt_pkrtz(h0, h1));     \
            pk.y = __builtin_bit_cast(unsigned int,                            \
                                      __builtin_amdgcn_cvt_pkrtz(h2, h3));     \
            *(uint2*)(lds + ((CUR) ^ 1) * 8192 + wboff[mt]) = pk;              \
        }                                                                      \
        {                                                                      \
            int sp = (SIDX) + 2;                                               \
            if (sp > S_ - 1) sp = S_ - 1;                                      \
            _Pragma("unroll") for (int mt = 0; mt < 4; ++mt)                   \
                CV[mt] =                                                       \
                    *(const f32x4*)(xwl + (size_t)sp * 16384 + mt * 16);       \
        }                                                                      \
        __syncthreads();                                                       \
    }

    for (int s = 0; s < S_; s += 2) {
        STEP(0, cA, s)
        STEP(1, cB, s + 1)
    }
#undef STEP

#pragma unroll
    for (int mt = 0; mt < 4; ++mt) {
        float4 o;
        o.x = hs[mt][0]; o.y = hs[mt][1]; o.z = hs[mt][2]; o.w = hs[mt][3];
        *(float4*)(hsum_out + (size_t)(bbase + n) * H_ + rowbase + mt * 16 +
                   hi * 4) = o;
    }
}

// ---------------------------------------------------------------------------
// Kernel D: summed logits = hsum @ W_out^T + S*b_out, then log_softmax.
// ---------------------------------------------------------------------------
__global__ void out_kernel(const float* __restrict__ hsum,
                           const float* __restrict__ W_out,
                           const float* __restrict__ b_out,
                           float* __restrict__ out) {
    int b = threadIdx.x;
    if (b >= B_) return;
    float logits[C_];
#pragma unroll
    for (int c = 0; c < C_; ++c) {
        float acc = 0.0f;
        for (int k = 0; k < H_; ++k)
            acc = fmaf(hsum[b * H_ + k], W_out[c * H_ + k], acc);
        logits[c] = acc + (float)S_ * b_out[c];
    }
    float m = logits[0];
#pragma unroll
    for (int c = 1; c < C_; ++c) m = fmaxf(m, logits[c]);
    float sum = 0.0f;
#pragma unroll
    for (int c = 0; c < C_; ++c) sum += expf(logits[c] - m);
    float lse = logf(sum);
#pragma unroll
    for (int c = 0; c < C_; ++c) out[b * C_ + c] = logits[c] - m - lse;
}

// ---------------------------------------------------------------------------
extern "C" void kernel_launch(void* const* d_in, const int* in_sizes, int n_in,
                              void* d_out, int out_size, void* d_ws,
                              size_t ws_size, hipStream_t stream) {
    const int* idx = (const int*)d_in[0];
    const float* emb = (const float*)d_in[1];
    const float* W_ih = (const float*)d_in[2];
    const float* W_hh = (const float*)d_in[3];
    const float* b_ih = (const float*)d_in[4];
    const float* b_hh = (const float*)d_in[5];
    const float* W_out = (const float*)d_in[6];
    const float* b_out = (const float*)d_in[7];
    float* out = (float*)d_out;

    float* ws = (float*)d_ws;
    float* WT = ws;                           // E*H
    float* xw = WT + E_ * H_;                 // S*B*H
    float* hsum = xw + (size_t)S_ * B_ * H_;  // B*H

    hipLaunchKernelGGL(transpose_kernel, dim3((E_ * H_ + 255) / 256), dim3(256),
                       0, stream, W_ih, WT);
    hipLaunchKernelGGL(xw_kernel, dim3((S_ * B_) / 64), dim3(256), 0, stream,
                       idx, emb, WT, b_ih, b_hh, xw);
    hipLaunchKernelGGL(rnn_kernel, dim3(4), dim3(256), 0, stream, xw, W_hh,
                       hsum);
    hipLaunchKernelGGL(out_kernel, dim3(1), dim3(64), 0, stream, hsum, W_out,
                       b_out, out);
}

// Round 7
// 325.364 us; speedup vs baseline: 1.4473x; 1.4473x over previous
//
#include <hip/hip_runtime.h>
#include <stdint.h>

#define S_ 512
#define B_ 64
#define V_ 50000
#define E_ 300
#define H_ 256
#define C_ 5
#define KP_ 320  // E padded to 10 slices of K=32

typedef _Float16 h8_t __attribute__((ext_vector_type(8)));
typedef float f32x4 __attribute__((ext_vector_type(4)));

// tanh(x) = 1 - 2/(e^{2x}+1); e^{2x}=2^{2x*log2e}. No clamp needed:
// x->-inf: e->0 -> -1; x->+inf: e->inf, rcp(inf)=0 -> +1.
__device__ __forceinline__ float fast_tanh(float x) {
    float e = __builtin_amdgcn_exp2f(x * 2.88539008177793f);  // 2*log2(e)
    return fmaf(-2.0f, __builtin_amdgcn_rcpf(e + 1.0f), 1.0f);
}

// ---------------------------------------------------------------------------
// Kernel A: pack W_ih (H,E) f32 -> WB f16 in B-fragment order for the xw GEMM.
// WB frag index (nt, ks): lane l holds B[k=ks*32+(l>>4)*8+j][col=nt*16+(l&15)]
// where B[k][col] = W_ih[col][k]; k >= 300 zero-padded.
// ---------------------------------------------------------------------------
__global__ void wb_prep_kernel(const float* __restrict__ W_ih,
                               uint4* __restrict__ WB) {
    int g = blockIdx.x * 256 + threadIdx.x;  // 0 .. 16*10*64-1
    if (g >= 16 * 10 * 64) return;
    int l = g & 63;
    int ks = (g >> 6) % 10;
    int nt = g / 640;
    int h = nt * 16 + (l & 15);
    int e0 = ks * 32 + (l >> 4) * 8;
    h8_t v;
#pragma unroll
    for (int j = 0; j < 8; ++j) {
        int e = e0 + j;
        v[j] = (e < E_) ? (_Float16)W_ih[(size_t)h * E_ + e] : (_Float16)0.0f;
    }
    WB[g] = __builtin_bit_cast(uint4, v);
}

// ---------------------------------------------------------------------------
// Kernel B: xw[s,b,h] = sum_e emb[idx[s,b],e]*W_ih[h,e] + b_ih[h] + b_hh[h]
// MFMA version: 512 blocks x 512 threads (8 waves). Block does 64 (s,b) rows
// x all 256 h. Embedding rows staged DIRECTLY into A-fragment-ordered f16
// LDS (40KB, K padded to 320). Wave w computes cols 32w..32w+31:
// 4 M-tiles x 2 N-tiles x 10 K-slices = 80 MFMA. Bias pre-loaded as C-init.
// ---------------------------------------------------------------------------
__global__ __launch_bounds__(512, 2) void xw_kernel(
    const int* __restrict__ idx, const float* __restrict__ emb,
    const uint4* __restrict__ WB, const float* __restrict__ b_ih,
    const float* __restrict__ b_hh, float* __restrict__ xw) {
    // A fragments: index (mt*10+ks)*64 + lane, 16B each = 40 KB
    __shared__ uint4 Afrag[4 * 10 * 64];
    const int tid = threadIdx.x;
    const int w = tid >> 6;  // wave 0..7
    const int l = tid & 63;
    const int n = l & 15;
    const int hi = l >> 4;
    const int base = blockIdx.x * 64;

    // ---- stage A fragments (64 rows x 40 chunks of 8 e-values) ----
    for (int cc = tid; cc < 64 * 40; cc += 512) {
        int m = cc / 40;
        int c = cc - m * 40;  // chunk: e = 8c..8c+7
        int ks = c >> 2;
        int hic = c & 3;
        const float* src = emb + (size_t)idx[base + m] * E_ + 8 * c;
        h8_t v;
        if (c < 37) {
            float4 f0 = *(const float4*)src;
            float4 f1 = *(const float4*)(src + 4);
            v[0] = (_Float16)f0.x; v[1] = (_Float16)f0.y;
            v[2] = (_Float16)f0.z; v[3] = (_Float16)f0.w;
            v[4] = (_Float16)f1.x; v[5] = (_Float16)f1.y;
            v[6] = (_Float16)f1.z; v[7] = (_Float16)f1.w;
        } else if (c == 37) {  // e = 296..303: 4 real + 4 pad
            float4 f0 = *(const float4*)src;
            v[0] = (_Float16)f0.x; v[1] = (_Float16)f0.y;
            v[2] = (_Float16)f0.z; v[3] = (_Float16)f0.w;
            v[4] = (_Float16)0.0f; v[5] = (_Float16)0.0f;
            v[6] = (_Float16)0.0f; v[7] = (_Float16)0.0f;
        } else {  // e >= 304: pad
            v = (h8_t)(_Float16)0.0f;
        }
        int fl = (hic << 4) | (m & 15);
        int mt = m >> 4;
        Afrag[(mt * 10 + ks) * 64 + fl] = __builtin_bit_cast(uint4, v);
    }
    __syncthreads();

    // ---- compute: wave w -> cols 32w .. 32w+31 (nt = 2w, 2w+1) ----
    float bias0 = b_ih[w * 32 + n] + b_hh[w * 32 + n];
    float bias1 = b_ih[w * 32 + 16 + n] + b_hh[w * 32 + 16 + n];
    f32x4 c[4][2];
#pragma unroll
    for (int mt = 0; mt < 4; ++mt) {
        c[mt][0] = (f32x4)bias0;
        c[mt][1] = (f32x4)bias1;
    }

    const uint4* wb0 = WB + ((2 * w) * 10) * 64 + l;
    const uint4* wb1 = WB + ((2 * w + 1) * 10) * 64 + l;
#pragma unroll
    for (int ks = 0; ks < 10; ++ks) {
        h8_t b0 = __builtin_bit_cast(h8_t, wb0[ks * 64]);
        h8_t b1 = __builtin_bit_cast(h8_t, wb1[ks * 64]);
#pragma unroll
        for (int mt = 0; mt < 4; ++mt) {
            h8_t a = __builtin_bit_cast(h8_t, Afrag[(mt * 10 + ks) * 64 + l]);
            c[mt][0] = __builtin_amdgcn_mfma_f32_16x16x32_f16(a, b0, c[mt][0],
                                                              0, 0, 0);
            c[mt][1] = __builtin_amdgcn_mfma_f32_16x16x32_f16(a, b1, c[mt][1],
                                                              0, 0, 0);
        }
    }

    // ---- store: D col=l&15, row=(l>>4)*4+r ----
#pragma unroll
    for (int mt = 0; mt < 4; ++mt)
#pragma unroll
        for (int q = 0; q < 2; ++q) {
            float* op =
                xw + (size_t)(base + mt * 16 + hi * 4) * H_ + w * 32 + q * 16 + n;
#pragma unroll
            for (int r = 0; r < 4; ++r) op[(size_t)r * H_] = c[mt][q][r];
        }
}

// ---------------------------------------------------------------------------
// Kernel C: MFMA recurrence (R4 config, measured 279us). 4 blocks x 16 batch
// cols, 512 threads (8 waves, 2 waves/SIMD). Per step:
// D[256,16] = W_hh*H + xw (xw = C operand).
//   wave w owns rows 32w..32w+31 (2 M-tiles): A = 2x8 h8_t = 64 regs.
//   H in LDS in B-FRAGMENT ORDER (conflict-free both sides):
//     byte(k, col n) = (k>>5)*1024 + ((k>>3)&3)*256 + n*16 + (k&7)*2
//   read:  lane l, slice ks -> b128 at ks*1024 + 16*l  (linear: 0 conflict)
//   write: lane (hi,n), tile mt -> b64 at const + n*16 (2-way = free)
//   Epilogue: slim tanh, hsum in regs, cvt_pkrtz pack, b64 writes.
//   xw prefetched 2 steps ahead into future C registers.
//   One barrier per step; H double-buffered (2x8KB).
// ---------------------------------------------------------------------------
__global__ __launch_bounds__(512, 2) void rnn_kernel(
    const float* __restrict__ xw, const float* __restrict__ W_hh,
    float* __restrict__ hsum_out) {
    const int tid = threadIdx.x;
    const int w = tid >> 6;  // wave 0..7
    const int l = tid & 63;
    const int n = l & 15;   // batch col within block / A row / B col
    const int hi = l >> 4;  // k-group
    const int bbase = blockIdx.x * 16;
    const int rowbase = w * 32;

    __shared__ __attribute__((aligned(16))) unsigned char Hl[2][8192];
    char* lds = (char*)Hl;

    // ---- A fragments: W_hh rows rowbase..rowbase+31 as f16 ----
    h8_t a[2][8];
#pragma unroll
    for (int mt = 0; mt < 2; ++mt) {
        const float* wr = W_hh + (size_t)(rowbase + mt * 16 + n) * H_;
#pragma unroll
        for (int ks = 0; ks < 8; ++ks) {
            const float* wp = wr + ks * 32 + hi * 8;
            float4 f0 = *(const float4*)wp;
            float4 f1 = *(const float4*)(wp + 4);
            h8_t v;
            v[0] = (_Float16)f0.x; v[1] = (_Float16)f0.y;
            v[2] = (_Float16)f0.z; v[3] = (_Float16)f0.w;
            v[4] = (_Float16)f1.x; v[5] = (_Float16)f1.y;
            v[6] = (_Float16)f1.z; v[7] = (_Float16)f1.w;
            a[mt][ks] = v;
        }
    }

    // H'-write byte offsets (within a buffer): rows k0..k0+3, col n
    int wboff[2];
#pragma unroll
    for (int mt = 0; mt < 2; ++mt) {
        int k0 = rowbase + mt * 16 + hi * 4;
        wboff[mt] = ((k0 >> 5) << 10) + (((k0 >> 3) & 3) << 8) + (n << 4) +
                    ((k0 & 7) << 1);
    }

    // zero H buffer 0 (8 KB = 2048 dwords)
    for (int t = tid; t < 2048; t += 512) ((unsigned int*)Hl)[t] = 0u;

    f32x4 hs[2];
    hs[0] = (f32x4)0.0f;
    hs[1] = (f32x4)0.0f;

    // per-lane xw element base: xw[s][bbase+n][rowbase + mt*16 + hi*4 + r]
    const float* xwl = xw + (size_t)(bbase + n) * H_ + rowbase + hi * 4;
    // xw doubles as the MFMA C operand (prefetched 2 steps ahead)
    f32x4 cA[2], cB[2];
#pragma unroll
    for (int mt = 0; mt < 2; ++mt) {
        cA[mt] = *(const f32x4*)(xwl + mt * 16);          // s = 0
        cB[mt] = *(const f32x4*)(xwl + 16384 + mt * 16);  // s = 1
    }
    __syncthreads();

#define STEP(CUR, CV, SIDX)                                                    \
    {                                                                          \
        h8_t bf[8];                                                            \
        _Pragma("unroll") for (int ks = 0; ks < 8; ++ks)                       \
            bf[ks] = *(const h8_t*)(lds + (CUR)*8192 + ks * 1024 + l * 16);    \
        _Pragma("unroll") for (int ks = 0; ks < 8; ++ks) {                     \
            CV[0] = __builtin_amdgcn_mfma_f32_16x16x32_f16(a[0][ks], bf[ks],   \
                                                           CV[0], 0, 0, 0);    \
            CV[1] = __builtin_amdgcn_mfma_f32_16x16x32_f16(a[1][ks], bf[ks],   \
                                                           CV[1], 0, 0, 0);    \
        }                                                                      \
        _Pragma("unroll") for (int mt = 0; mt < 2; ++mt) {                     \
            float h0 = fast_tanh(CV[mt][0]);                                   \
            float h1 = fast_tanh(CV[mt][1]);                                   \
            float h2 = fast_tanh(CV[mt][2]);                                   \
            float h3 = fast_tanh(CV[mt][3]);                                   \
            hs[mt][0] += h0; hs[mt][1] += h1;                                  \
            hs[mt][2] += h2; hs[mt][3] += h3;                                  \
            uint2 pk;                                                          \
            pk.x = __builtin_bit_cast(unsigned int,                            \
                                      __builtin_amdgcn_cvt_pkrtz(h0, h1));     \
            pk.y = __builtin_bit_cast(unsigned int,                            \
                                      __builtin_amdgcn_cvt_pkrtz(h2, h3));     \
            *(uint2*)(lds + ((CUR) ^ 1) * 8192 + wboff[mt]) = pk;              \
        }                                                                      \
        {                                                                      \
            int sp = (SIDX) + 2;                                               \
            if (sp > S_ - 1) sp = S_ - 1;                                      \
            _Pragma("unroll") for (int mt = 0; mt < 2; ++mt)                   \
                CV[mt] =                                                       \
                    *(const f32x4*)(xwl + (size_t)sp * 16384 + mt * 16);       \
        }                                                                      \
        __syncthreads();                                                       \
    }

    for (int s = 0; s < S_; s += 2) {
        STEP(0, cA, s)
        STEP(1, cB, s + 1)
    }
#undef STEP

#pragma unroll
    for (int mt = 0; mt < 2; ++mt) {
        float4 o;
        o.x = hs[mt][0]; o.y = hs[mt][1]; o.z = hs[mt][2]; o.w = hs[mt][3];
        *(float4*)(hsum_out + (size_t)(bbase + n) * H_ + rowbase + mt * 16 +
                   hi * 4) = o;
    }
}

// ---------------------------------------------------------------------------
// Kernel D: summed logits = hsum @ W_out^T + S*b_out, then log_softmax.
// ---------------------------------------------------------------------------
__global__ void out_kernel(const float* __restrict__ hsum,
                           const float* __restrict__ W_out,
                           const float* __restrict__ b_out,
                           float* __restrict__ out) {
    int b = threadIdx.x;
    if (b >= B_) return;
    float logits[C_];
#pragma unroll
    for (int c = 0; c < C_; ++c) {
        float acc = 0.0f;
        for (int k = 0; k < H_; ++k)
            acc = fmaf(hsum[b * H_ + k], W_out[c * H_ + k], acc);
        logits[c] = acc + (float)S_ * b_out[c];
    }
    float m = logits[0];
#pragma unroll
    for (int c = 1; c < C_; ++c) m = fmaxf(m, logits[c]);
    float sum = 0.0f;
#pragma unroll
    for (int c = 0; c < C_; ++c) sum += expf(logits[c] - m);
    float lse = logf(sum);
#pragma unroll
    for (int c = 0; c < C_; ++c) out[b * C_ + c] = logits[c] - m - lse;
}

// ---------------------------------------------------------------------------
extern "C" void kernel_launch(void* const* d_in, const int* in_sizes, int n_in,
                              void* d_out, int out_size, void* d_ws,
                              size_t ws_size, hipStream_t stream) {
    const int* idx = (const int*)d_in[0];
    const float* emb = (const float*)d_in[1];
    const float* W_ih = (const float*)d_in[2];
    const float* W_hh = (const float*)d_in[3];
    const float* b_ih = (const float*)d_in[4];
    const float* b_hh = (const float*)d_in[5];
    const float* W_out = (const float*)d_in[6];
    const float* b_out = (const float*)d_in[7];
    float* out = (float*)d_out;

    float* ws = (float*)d_ws;
    uint4* WB = (uint4*)ws;                    // 16*10*64 uint4 = 160 KB
    float* xw = ws + 40960;                    // S*B*H floats
    float* hsum = xw + (size_t)S_ * B_ * H_;   // B*H floats

    hipLaunchKernelGGL(wb_prep_kernel, dim3(40), dim3(256), 0, stream, W_ih,
                       WB);
    hipLaunchKernelGGL(xw_kernel, dim3((S_ * B_) / 64), dim3(512), 0, stream,
                       idx, emb, WB, b_ih, b_hh, xw);
    hipLaunchKernelGGL(rnn_kernel, dim3(4), dim3(512), 0, stream, xw, W_hh,
                       hsum);
    hipLaunchKernelGGL(out_kernel, dim3(1), dim3(64), 0, stream, hsum, W_out,
                       b_out, out);
}

// Round 8
// 324.675 us; speedup vs baseline: 1.4504x; 1.0021x over previous
//
#include <hip/hip_runtime.h>
#include <stdint.h>

#define S_ 512
#define B_ 64
#define V_ 50000
#define E_ 300
#define H_ 256
#define C_ 5

typedef _Float16 h8_t __attribute__((ext_vector_type(8)));
typedef float f32x4 __attribute__((ext_vector_type(4)));

// tanh(x) = 1 - 2/(e^{2x}+1); e^{2x}=2^{2x*log2e}. No clamp needed:
// x->-inf: e->0 -> -1; x->+inf: e->inf, rcp(inf)=0 -> +1.
__device__ __forceinline__ float fast_tanh(float x) {
    float e = __builtin_amdgcn_exp2f(x * 2.88539008177793f);  // 2*log2(e)
    return fmaf(-2.0f, __builtin_amdgcn_rcpf(e + 1.0f), 1.0f);
}

// ---------------------------------------------------------------------------
// Kernel A: pack W_ih (H,E) f32 -> WB f16 in B-fragment order for the xw GEMM.
// ---------------------------------------------------------------------------
__global__ void wb_prep_kernel(const float* __restrict__ W_ih,
                               uint4* __restrict__ WB) {
    int g = blockIdx.x * 256 + threadIdx.x;  // 0 .. 16*10*64-1
    if (g >= 16 * 10 * 64) return;
    int l = g & 63;
    int ks = (g >> 6) % 10;
    int nt = g / 640;
    int h = nt * 16 + (l & 15);
    int e0 = ks * 32 + (l >> 4) * 8;
    h8_t v;
#pragma unroll
    for (int j = 0; j < 8; ++j) {
        int e = e0 + j;
        v[j] = (e < E_) ? (_Float16)W_ih[(size_t)h * E_ + e] : (_Float16)0.0f;
    }
    WB[g] = __builtin_bit_cast(uint4, v);
}

// ---------------------------------------------------------------------------
// Kernel B: xw[s,b,h] = sum_e emb[idx[s,b],e]*W_ih[h,e] + b_ih[h] + b_hh[h]
// MFMA version: 512 blocks x 512 threads (8 waves).
// ---------------------------------------------------------------------------
__global__ __launch_bounds__(512, 2) void xw_kernel(
    const int* __restrict__ idx, const float* __restrict__ emb,
    const uint4* __restrict__ WB, const float* __restrict__ b_ih,
    const float* __restrict__ b_hh, float* __restrict__ xw) {
    __shared__ uint4 Afrag[4 * 10 * 64];
    const int tid = threadIdx.x;
    const int w = tid >> 6;  // wave 0..7
    const int l = tid & 63;
    const int n = l & 15;
    const int hi = l >> 4;
    const int base = blockIdx.x * 64;

    for (int cc = tid; cc < 64 * 40; cc += 512) {
        int m = cc / 40;
        int c = cc - m * 40;  // chunk: e = 8c..8c+7
        int ks = c >> 2;
        int hic = c & 3;
        const float* src = emb + (size_t)idx[base + m] * E_ + 8 * c;
        h8_t v;
        if (c < 37) {
            float4 f0 = *(const float4*)src;
            float4 f1 = *(const float4*)(src + 4);
            v[0] = (_Float16)f0.x; v[1] = (_Float16)f0.y;
            v[2] = (_Float16)f0.z; v[3] = (_Float16)f0.w;
            v[4] = (_Float16)f1.x; v[5] = (_Float16)f1.y;
            v[6] = (_Float16)f1.z; v[7] = (_Float16)f1.w;
        } else if (c == 37) {
            float4 f0 = *(const float4*)src;
            v[0] = (_Float16)f0.x; v[1] = (_Float16)f0.y;
            v[2] = (_Float16)f0.z; v[3] = (_Float16)f0.w;
            v[4] = (_Float16)0.0f; v[5] = (_Float16)0.0f;
            v[6] = (_Float16)0.0f; v[7] = (_Float16)0.0f;
        } else {
            v = (h8_t)(_Float16)0.0f;
        }
        int fl = (hic << 4) | (m & 15);
        int mt = m >> 4;
        Afrag[(mt * 10 + ks) * 64 + fl] = __builtin_bit_cast(uint4, v);
    }
    __syncthreads();

    float bias0 = b_ih[w * 32 + n] + b_hh[w * 32 + n];
    float bias1 = b_ih[w * 32 + 16 + n] + b_hh[w * 32 + 16 + n];
    f32x4 c[4][2];
#pragma unroll
    for (int mt = 0; mt < 4; ++mt) {
        c[mt][0] = (f32x4)bias0;
        c[mt][1] = (f32x4)bias1;
    }

    const uint4* wb0 = WB + ((2 * w) * 10) * 64 + l;
    const uint4* wb1 = WB + ((2 * w + 1) * 10) * 64 + l;
#pragma unroll
    for (int ks = 0; ks < 10; ++ks) {
        h8_t b0 = __builtin_bit_cast(h8_t, wb0[ks * 64]);
        h8_t b1 = __builtin_bit_cast(h8_t, wb1[ks * 64]);
#pragma unroll
        for (int mt = 0; mt < 4; ++mt) {
            h8_t a = __builtin_bit_cast(h8_t, Afrag[(mt * 10 + ks) * 64 + l]);
            c[mt][0] = __builtin_amdgcn_mfma_f32_16x16x32_f16(a, b0, c[mt][0],
                                                              0, 0, 0);
            c[mt][1] = __builtin_amdgcn_mfma_f32_16x16x32_f16(a, b1, c[mt][1],
                                                              0, 0, 0);
        }
    }

#pragma unroll
    for (int mt = 0; mt < 4; ++mt)
#pragma unroll
        for (int q = 0; q < 2; ++q) {
            float* op =
                xw + (size_t)(base + mt * 16 + hi * 4) * H_ + w * 32 + q * 16 + n;
#pragma unroll
            for (int r = 0; r < 4; ++r) op[(size_t)r * H_] = c[mt][q][r];
        }
}

// ---------------------------------------------------------------------------
// Kernel C: MFMA recurrence. 4 blocks x 16 batch cols, 512 threads (8 waves,
// 2 waves/SIMD). Per step: D[256,16] = W_hh*H + xw (xw = C operand).
//
// R8 changes vs R7 (structure otherwise identical, measured 279us):
//  1. LIGHT BARRIER: s_waitcnt lgkmcnt(0) + raw s_barrier instead of
//     __syncthreads(). __syncthreads drains vmcnt(0), forcing every step to
//     eat the ~900cyc HBM latency of the just-issued xw prefetch. The
//     prefetch loads now ride across the barrier (T4: never vmcnt(0) in the
//     main loop). LDS correctness needs only lgkmcnt: reads/writes of each
//     wave are complete before it arrives; buffers alternate per step.
//  2. PREFETCH AT TOP of step, unroll x4 with cv[4] rotation: STEP I loads
//     s+2 into cv[(I+2)&3], which was last read 2 steps ago (WAR-safe) and
//     is next read 2 steps later (~2000cyc > 900cyc HBM latency -> the
//     compiler's fine-grained vmcnt before first MFMA use is ~free).
//
//   H in LDS in B-FRAGMENT ORDER (conflict-free both sides):
//     byte(k, col n) = (k>>5)*1024 + ((k>>3)&3)*256 + n*16 + (k&7)*2
//   read:  lane l, slice ks -> b128 at ks*1024 + 16*l  (linear: 0 conflict)
//   write: lane (hi,n), tile mt -> b64 at const + n*16 (2-way = free)
// ---------------------------------------------------------------------------
__global__ __launch_bounds__(512, 2) void rnn_kernel(
    const float* __restrict__ xw, const float* __restrict__ W_hh,
    float* __restrict__ hsum_out) {
    const int tid = threadIdx.x;
    const int w = tid >> 6;  // wave 0..7
    const int l = tid & 63;
    const int n = l & 15;   // batch col within block / A row / B col
    const int hi = l >> 4;  // k-group
    const int bbase = blockIdx.x * 16;
    const int rowbase = w * 32;

    __shared__ __attribute__((aligned(16))) unsigned char Hl[2][8192];
    char* lds = (char*)Hl;

    // ---- A fragments: W_hh rows rowbase..rowbase+31 as f16 ----
    h8_t a[2][8];
#pragma unroll
    for (int mt = 0; mt < 2; ++mt) {
        const float* wr = W_hh + (size_t)(rowbase + mt * 16 + n) * H_;
#pragma unroll
        for (int ks = 0; ks < 8; ++ks) {
            const float* wp = wr + ks * 32 + hi * 8;
            float4 f0 = *(const float4*)wp;
            float4 f1 = *(const float4*)(wp + 4);
            h8_t v;
            v[0] = (_Float16)f0.x; v[1] = (_Float16)f0.y;
            v[2] = (_Float16)f0.z; v[3] = (_Float16)f0.w;
            v[4] = (_Float16)f1.x; v[5] = (_Float16)f1.y;
            v[6] = (_Float16)f1.z; v[7] = (_Float16)f1.w;
            a[mt][ks] = v;
        }
    }

    // H'-write byte offsets (within a buffer): rows k0..k0+3, col n
    int wboff[2];
#pragma unroll
    for (int mt = 0; mt < 2; ++mt) {
        int k0 = rowbase + mt * 16 + hi * 4;
        wboff[mt] = ((k0 >> 5) << 10) + (((k0 >> 3) & 3) << 8) + (n << 4) +
                    ((k0 & 7) << 1);
    }

    // zero H buffer 0 (8 KB = 2048 dwords)
    for (int t = tid; t < 2048; t += 512) ((unsigned int*)Hl)[t] = 0u;

    f32x4 hs[2];
    hs[0] = (f32x4)0.0f;
    hs[1] = (f32x4)0.0f;

    // per-lane xw element base: xw[s][bbase+n][rowbase + mt*16 + hi*4 + r]
    const float* xwl = xw + (size_t)(bbase + n) * H_ + rowbase + hi * 4;
    // 4-slot rotation of xw-as-C-operand buffers
    f32x4 cv[4][2];
    cv[0][0] = *(const f32x4*)(xwl);                  // s = 0
    cv[0][1] = *(const f32x4*)(xwl + 16);
    cv[1][0] = *(const f32x4*)(xwl + 16384);          // s = 1
    cv[1][1] = *(const f32x4*)(xwl + 16384 + 16);
    __syncthreads();  // full barrier once (zero-init visible)

#define STEP(CUR, I, SBASE)                                                    \
    {                                                                          \
        /* prefetch s+2 into the slot dead for the next 2 steps */             \
        int sp = (SBASE) + 2;                                                  \
        if (sp > S_ - 1) sp = S_ - 1;                                          \
        cv[(I + 2) & 3][0] = *(const f32x4*)(xwl + (size_t)sp * 16384);        \
        cv[(I + 2) & 3][1] = *(const f32x4*)(xwl + (size_t)sp * 16384 + 16);   \
        h8_t bf[8];                                                            \
        _Pragma("unroll") for (int ks = 0; ks < 8; ++ks)                       \
            bf[ks] = *(const h8_t*)(lds + (CUR)*8192 + ks * 1024 + l * 16);    \
        _Pragma("unroll") for (int ks = 0; ks < 8; ++ks) {                     \
            cv[I][0] = __builtin_amdgcn_mfma_f32_16x16x32_f16(                 \
                a[0][ks], bf[ks], cv[I][0], 0, 0, 0);                          \
            cv[I][1] = __builtin_amdgcn_mfma_f32_16x16x32_f16(                 \
                a[1][ks], bf[ks], cv[I][1], 0, 0, 0);                          \
        }                                                                      \
        _Pragma("unroll") for (int mt = 0; mt < 2; ++mt) {                     \
            float h0 = fast_tanh(cv[I][mt][0]);                                \
            float h1 = fast_tanh(cv[I][mt][1]);                                \
            float h2 = fast_tanh(cv[I][mt][2]);                                \
            float h3 = fast_tanh(cv[I][mt][3]);                                \
            hs[mt][0] += h0; hs[mt][1] += h1;                                  \
            hs[mt][2] += h2; hs[mt][3] += h3;                                  \
            uint2 pk;                                                          \
            pk.x = __builtin_bit_cast(unsigned int,                            \
                                      __builtin_amdgcn_cvt_pkrtz(h0, h1));     \
            pk.y = __builtin_bit_cast(unsigned int,                            \
                                      __builtin_amdgcn_cvt_pkrtz(h2, h3));     \
            *(uint2*)(lds + ((CUR) ^ 1) * 8192 + wboff[mt]) = pk;              \
        }                                                                      \
        asm volatile("s_waitcnt lgkmcnt(0)" ::: "memory");                     \
        __builtin_amdgcn_s_barrier();                                          \
    }

    for (int s = 0; s < S_; s += 4) {
        STEP(0, 0, s)
        STEP(1, 1, s + 1)
        STEP(0, 2, s + 2)
        STEP(1, 3, s + 3)
    }
#undef STEP

#pragma unroll
    for (int mt = 0; mt < 2; ++mt) {
        float4 o;
        o.x = hs[mt][0]; o.y = hs[mt][1]; o.z = hs[mt][2]; o.w = hs[mt][3];
        *(float4*)(hsum_out + (size_t)(bbase + n) * H_ + rowbase + mt * 16 +
                   hi * 4) = o;
    }
}

// ---------------------------------------------------------------------------
// Kernel D: summed logits = hsum @ W_out^T + S*b_out, then log_softmax.
// ---------------------------------------------------------------------------
__global__ void out_kernel(const float* __restrict__ hsum,
                           const float* __restrict__ W_out,
                           const float* __restrict__ b_out,
                           float* __restrict__ out) {
    int b = threadIdx.x;
    if (b >= B_) return;
    float logits[C_];
#pragma unroll
    for (int c = 0; c < C_; ++c) {
        float acc = 0.0f;
        for (int k = 0; k < H_; ++k)
            acc = fmaf(hsum[b * H_ + k], W_out[c * H_ + k], acc);
        logits[c] = acc + (float)S_ * b_out[c];
    }
    float m = logits[0];
#pragma unroll
    for (int c = 1; c < C_; ++c) m = fmaxf(m, logits[c]);
    float sum = 0.0f;
#pragma unroll
    for (int c = 0; c < C_; ++c) sum += expf(logits[c] - m);
    float lse = logf(sum);
#pragma unroll
    for (int c = 0; c < C_; ++c) out[b * C_ + c] = logits[c] - m - lse;
}

// ---------------------------------------------------------------------------
extern "C" void kernel_launch(void* const* d_in, const int* in_sizes, int n_in,
                              void* d_out, int out_size, void* d_ws,
                              size_t ws_size, hipStream_t stream) {
    const int* idx = (const int*)d_in[0];
    const float* emb = (const float*)d_in[1];
    const float* W_ih = (const float*)d_in[2];
    const float* W_hh = (const float*)d_in[3];
    const float* b_ih = (const float*)d_in[4];
    const float* b_hh = (const float*)d_in[5];
    const float* W_out = (const float*)d_in[6];
    const float* b_out = (const float*)d_in[7];
    float* out = (float*)d_out;

    float* ws = (float*)d_ws;
    uint4* WB = (uint4*)ws;                    // 16*10*64 uint4 = 160 KB
    float* xw = ws + 40960;                    // S*B*H floats
    float* hsum = xw + (size_t)S_ * B_ * H_;   // B*H floats

    hipLaunchKernelGGL(wb_prep_kernel, dim3(40), dim3(256), 0, stream, W_ih,
                       WB);
    hipLaunchKernelGGL(xw_kernel, dim3((S_ * B_) / 64), dim3(512), 0, stream,
                       idx, emb, WB, b_ih, b_hh, xw);
    hipLaunchKernelGGL(rnn_kernel, dim3(4), dim3(512), 0, stream, xw, W_hh,
                       hsum);
    hipLaunchKernelGGL(out_kernel, dim3(1), dim3(64), 0, stream, hsum, W_out,
                       b_out, out);
}